// Round 4
// baseline (157.501 us; speedup 1.0000x reference)
//
#include <hip/hip_runtime.h>
#include <hip/hip_bf16.h>
#include <math.h>

// Problem: B=4096, N=200, D=128, V=100000
//   h = gelu(x @ W_mu + b_mu)            (4096,128)
//   logits[b][n] = dot(h[b], emb[cand[b][n]]) + mu_bias[cand[b][n]]
//
// Inputs (fp32 unless noted): x(4096,128), candidates(4096,200) int32,
//   W_mu(128,128), b_mu(128), mu_bias(100000), emb_table(100000,128)
// Output: logits (4096,200) fp32.

#define BDIM 4096
#define NCAND 200
#define DDIM 128

// ---------------- Kernel A: h = gelu(x @ W + b) ----------------
// block = 256 threads, 8 rows per block. grid = 512.
// thread t: col = t & 127, rp = t >> 7 (0/1); computes rows rp, rp+2, rp+4, rp+6.
__global__ __launch_bounds__(256) void gelu_head_kernel(
    const float* __restrict__ x, const float* __restrict__ W,
    const float* __restrict__ bvec, float* __restrict__ h) {
  __shared__ float xs[8][DDIM];
  const int b0 = blockIdx.x * 8;
  const int t = threadIdx.x;

  // stage 8 x-rows (1024 floats = 256 float4) into LDS
  {
    const float4* xg = reinterpret_cast<const float4*>(x + (size_t)b0 * DDIM);
    float4* xsv = reinterpret_cast<float4*>(&xs[0][0]);
    xsv[t] = xg[t];
  }
  __syncthreads();

  const int col = t & 127;
  const int rp = t >> 7; // uniform per wave
  float acc0 = 0.f, acc1 = 0.f, acc2 = 0.f, acc3 = 0.f;
#pragma unroll 8
  for (int k = 0; k < DDIM; ++k) {
    const float w = W[k * DDIM + col]; // coalesced, L2-hot
    acc0 = fmaf(xs[rp + 0][k], w, acc0);
    acc1 = fmaf(xs[rp + 2][k], w, acc1);
    acc2 = fmaf(xs[rp + 4][k], w, acc2);
    acc3 = fmaf(xs[rp + 6][k], w, acc3);
  }
  const float bb = bvec[col];
  float v[4] = {acc0 + bb, acc1 + bb, acc2 + bb, acc3 + bb};
#pragma unroll
  for (int r = 0; r < 4; ++r) {
    const float u = v[r];
    const float g = 0.5f * u * (1.0f + erff(u * 0.70710678118654752f)); // exact GELU
    h[(size_t)(b0 + rp + 2 * r) * DDIM + col] = g;
  }
}

// ---------------- Kernel B: gather + batched dot ----------------
// One wave per half-row (100 candidates). 8192 waves, block=256 (4 waves),
// grid=2048. Within a wave: 4 groups of 16 lanes; each group handles one
// candidate per iteration (16 lanes x 32B = 512B coalesced row read).
__global__ __launch_bounds__(256) void gather_dot_kernel(
    const float* __restrict__ h, const int* __restrict__ cand,
    const float* __restrict__ bias, const float* __restrict__ emb,
    float* __restrict__ out) {
  const int wave = (blockIdx.x * 256 + threadIdx.x) >> 6;
  const int lane = threadIdx.x & 63;
  const int b = wave >> 1;
  const int half = wave & 1;
  const int l16 = lane & 15;
  const int grp = lane >> 4; // 0..3

  // h fragments: lane holds h[4*l16 .. +3] and h[64 + 4*l16 .. +3]
  const float4* hv = reinterpret_cast<const float4*>(h + (size_t)b * DDIM);
  const float4 h1 = hv[l16];
  const float4 h2 = hv[l16 + 16];

  const int nstart = half * 100;
  const int nend = nstart + 100;
  const int rowbase = b * NCAND;

  for (int n0 = nstart; n0 < nend; n0 += 64) {
    const int nseg = min(64, nend - n0); // 64 then 36; both multiples of 4
    int ci = 0;
    float bi = 0.f;
    if (lane < nseg) {
      ci = cand[rowbase + n0 + lane];
      bi = bias[ci]; // 4B gather from 400KB table (L2-resident)
    }
    const int iters = nseg >> 2;
#pragma unroll 4
    for (int i = 0; i < iters; ++i) {
      const int slot = i * 4 + grp;
      const int c = __shfl(ci, slot);
      const float4* ev = reinterpret_cast<const float4*>(emb + (size_t)c * DDIM);
      const float4 v1 = ev[l16];
      const float4 v2 = ev[l16 + 16];
      float acc = v1.x * h1.x;
      acc = fmaf(v1.y, h1.y, acc);
      acc = fmaf(v1.z, h1.z, acc);
      acc = fmaf(v1.w, h1.w, acc);
      acc = fmaf(v2.x, h2.x, acc);
      acc = fmaf(v2.y, h2.y, acc);
      acc = fmaf(v2.z, h2.z, acc);
      acc = fmaf(v2.w, h2.w, acc);
      // 16-lane butterfly (shared by all 4 groups)
      acc += __shfl_xor(acc, 1);
      acc += __shfl_xor(acc, 2);
      acc += __shfl_xor(acc, 4);
      acc += __shfl_xor(acc, 8);
      const float bslot = __shfl(bi, slot);
      if (l16 == 0) out[rowbase + n0 + slot] = acc + bslot;
    }
  }
}

extern "C" void kernel_launch(void* const* d_in, const int* in_sizes, int n_in,
                              void* d_out, int out_size, void* d_ws, size_t ws_size,
                              hipStream_t stream) {
  const float* x = (const float*)d_in[0];
  const int* candidates = (const int*)d_in[1];
  const float* W_mu = (const float*)d_in[2];
  const float* b_mu = (const float*)d_in[3];
  const float* mu_bias = (const float*)d_in[4];
  const float* emb_table = (const float*)d_in[5];
  float* out = (float*)d_out;

  float* h = (float*)d_ws; // 4096*128*4 = 2MB scratch

  gelu_head_kernel<<<BDIM / 8, 256, 0, stream>>>(x, W_mu, b_mu, h);
  gather_dot_kernel<<<(BDIM * 2) / 4, 256, 0, stream>>>(h, candidates, mu_bias,
                                                        emb_table, out);
}